// Round 1
// baseline (671.707 us; speedup 1.0000x reference)
//
#include <hip/hip_runtime.h>

#define B_ 16
#define D_ 64
#define T_ 4096
#define K_ 512
#define N_ (B_*T_)        // 65536 vectors
#define Q_ (B_*D_*T_)     // 4194304 quantized elements
#define ENC_OFF ((size_t)(2 + Q_))  // encodings start in d_out

// ws layout (bytes)
#define WS_LOSS    0        // double
#define WS_HIST    8        // int[512]
#define WS_AMB_CNT 2056     // int
#define WS_NE      2064     // float[512]
#define WS_IDX     4352     // int[65536]
#define WS_AMB     266496   // int[65536]

// ---------------- K0: init ws (hist=0, counters=0, ne[k] = ||e_k||^2) -------
__global__ __launch_bounds__(512) void k0_init(const float* __restrict__ cb,
                                               float* __restrict__ ne,
                                               int* __restrict__ hist,
                                               int* __restrict__ amb_cnt,
                                               double* __restrict__ loss) {
    int k = threadIdx.x;
    float s = 0.f;
#pragma unroll
    for (int d = 0; d < 64; ++d) { float c = cb[k*64 + d]; s = fmaf(c, c, s); }
    ne[k] = s;
    hist[k] = 0;
    if (k == 0) { *amb_cnt = 0; *loss = 0.0; }
}

// ---------------- K4: zero-fill encodings (float2: base only 8B-aligned) ----
__global__ void k4_zero(float2* __restrict__ enc2) {
    size_t i = (size_t)blockIdx.x * blockDim.x + threadIdx.x;
    size_t stride = (size_t)gridDim.x * blockDim.x;
    const size_t n2 = (size_t)N_ * K_ / 2;  // 16777216
    float2 z; z.x = 0.f; z.y = 0.f;
    for (size_t j = i; j < n2; j += stride) enc2[j] = z;
}

// ---------------- K1: fp32 argmin pass with top-2 margin ---------------------
__global__ __launch_bounds__(256) void k1_pass1(const float* __restrict__ in,
                                                const float* __restrict__ cb,
                                                const float* __restrict__ ne,
                                                int* __restrict__ idx_out,
                                                int* __restrict__ amb,
                                                int* __restrict__ amb_cnt) {
    int n = blockIdx.x * 256 + threadIdx.x;   // 0..65535
    int b = n >> 12, t = n & (T_ - 1);
    const float* xp = in + (size_t)b * D_ * T_ + t;

    float x[64];
#pragma unroll
    for (int d = 0; d < 64; ++d) x[d] = xp[d * T_];   // coalesced across lanes

    float min1 = 3.4e38f, min2 = 3.4e38f;
    int idx1 = 0;
    for (int k = 0; k < K_; ++k) {
        const float* c = cb + k * 64;                 // wave-uniform -> s_load
        float a0 = 0.f, a1 = 0.f, a2 = 0.f, a3 = 0.f;
#pragma unroll
        for (int d = 0; d < 64; d += 4) {
            a0 = fmaf(c[d + 0], x[d + 0], a0);
            a1 = fmaf(c[d + 1], x[d + 1], a1);
            a2 = fmaf(c[d + 2], x[d + 2], a2);
            a3 = fmaf(c[d + 3], x[d + 3], a3);
        }
        float dot = (a0 + a1) + (a2 + a3);
        float score = fmaf(-2.f, dot, ne[k]);         // ||e||^2 - 2 x.e
        if (score < min1) { min2 = min1; min1 = score; idx1 = k; }
        else if (score < min2) { min2 = score; }
    }
    idx_out[n] = idx1;
    // ambiguous: fp32 can't guarantee the exact-math argmin -> flag for f64
    if (min2 - min1 < 1e-4f) {
        int p = atomicAdd(amb_cnt, 1);
        amb[p] = n;
    }
}

// ---------------- K2: exact f64 refine for ambiguous rows -------------------
__global__ __launch_bounds__(64) void k2_refine(const float* __restrict__ in,
                                                const float* __restrict__ cb,
                                                const int* __restrict__ amb,
                                                const int* __restrict__ amb_cnt,
                                                int* __restrict__ idx_out) {
    int cnt = *amb_cnt;
    int lane = threadIdx.x;
    for (int i = blockIdx.x; i < cnt; i += gridDim.x) {
        int n = amb[i];
        int b = n >> 12, t = n & (T_ - 1);
        const float* xp = in + (size_t)b * D_ * T_ + t;
        double best = 1e300; int bidx = 0;
#pragma unroll
        for (int j = 0; j < 8; ++j) {
            int k = j * 64 + lane;
            const float* c = cb + k * 64;
            double dot = 0.0, nrm = 0.0;
            for (int d = 0; d < 64; ++d) {
                double cd = (double)c[d];
                dot = fma(cd, (double)xp[d * T_], dot);
                nrm = fma(cd, cd, nrm);
            }
            double score = nrm - 2.0 * dot;
            if (score < best) { best = score; bidx = k; }  // j asc => k asc per lane
        }
        // wave argmin reduce; tie -> lower index (np.argmin semantics)
        for (int off = 32; off > 0; off >>= 1) {
            double ob = __shfl_down(best, off);
            int oi = __shfl_down(bidx, off);
            if (ob < best || (ob == best && oi < bidx)) { best = ob; bidx = oi; }
        }
        if (lane == 0) idx_out[n] = bidx;
    }
}

// ---------------- K3: quantized output, loss partials, hist, one-hot ones ---
__global__ __launch_bounds__(256) void k3_outputs(const float* __restrict__ in,
                                                  const float* __restrict__ cb,
                                                  const int* __restrict__ idx_arr,
                                                  float* __restrict__ out,
                                                  int* __restrict__ hist,
                                                  double* __restrict__ loss) {
    int n = blockIdx.x * 256 + threadIdx.x;
    int b = n >> 12, t = n & (T_ - 1);
    const float* xp = in + (size_t)b * D_ * T_ + t;
    float* qp = out + 1 + (size_t)b * D_ * T_ + t;
    int idx = idx_arr[n];
    const float4* c4 = (const float4*)(cb + idx * 64);  // codebook rows 16B-aligned

    float lsum = 0.f;
#pragma unroll
    for (int d4 = 0; d4 < 16; ++d4) {
        float4 q = c4[d4];
        float qe[4] = {q.x, q.y, q.z, q.w};
#pragma unroll
        for (int e = 0; e < 4; ++e) {
            int d = d4 * 4 + e;
            float xv = xp[d * T_];
            float diff = qe[e] - xv;              // replicate (q - x) in fp32
            lsum = fmaf(diff, diff, lsum);
            qp[d * T_] = xv + diff;               // straight-through: x + (q - x)
        }
    }

    atomicAdd(&hist[idx], 1);
    out[ENC_OFF + (size_t)n * K_ + idx] = 1.0f;   // one-hot (zeros written by K4)

    // block-reduce lsum -> one f64 atomic per block
#pragma unroll
    for (int off = 32; off > 0; off >>= 1) lsum += __shfl_down(lsum, off);
    __shared__ float wsum[4];
    int wid = threadIdx.x >> 6;
    if ((threadIdx.x & 63) == 0) wsum[wid] = lsum;
    __syncthreads();
    if (threadIdx.x == 0) {
        double s = (double)wsum[0] + (double)wsum[1] + (double)wsum[2] + (double)wsum[3];
        atomicAdd(loss, s);
    }
}

// ---------------- K6: finalize loss + perplexity ----------------------------
__global__ __launch_bounds__(512) void k6_final(const int* __restrict__ hist,
                                                const double* __restrict__ loss,
                                                float* __restrict__ out) {
    __shared__ double sh[512];
    int k = threadIdx.x;
    double p = (double)hist[k] / (double)N_;
    sh[k] = p * log(p + 1e-10);
    __syncthreads();
    for (int s = 256; s > 0; s >>= 1) {
        if (k < s) sh[k] += sh[k + s];
        __syncthreads();
    }
    if (k == 0) {
        out[1 + Q_] = (float)exp(-sh[0]);                    // perplexity
        out[0] = (float)(1.25 * (*loss) / (double)Q_);       // q_loss + 0.25*e_loss
    }
}

extern "C" void kernel_launch(void* const* d_in, const int* in_sizes, int n_in,
                              void* d_out, int out_size, void* d_ws, size_t ws_size,
                              hipStream_t stream) {
    const float* in = (const float*)d_in[0];   // [16, 64, 4096] fp32
    const float* cb = (const float*)d_in[1];   // [512, 64] fp32
    float* out = (float*)d_out;
    char* ws = (char*)d_ws;

    double* loss  = (double*)(ws + WS_LOSS);
    int* hist     = (int*)(ws + WS_HIST);
    int* amb_cnt  = (int*)(ws + WS_AMB_CNT);
    float* ne     = (float*)(ws + WS_NE);
    int* idx      = (int*)(ws + WS_IDX);
    int* amb      = (int*)(ws + WS_AMB);

    k0_init<<<1, 512, 0, stream>>>(cb, ne, hist, amb_cnt, loss);
    k4_zero<<<2048, 256, 0, stream>>>((float2*)(out + ENC_OFF));
    k1_pass1<<<N_ / 256, 256, 0, stream>>>(in, cb, ne, idx, amb, amb_cnt);
    k2_refine<<<512, 64, 0, stream>>>(in, cb, amb, amb_cnt, idx);
    k3_outputs<<<N_ / 256, 256, 0, stream>>>(in, cb, idx, out, hist, loss);
    k6_final<<<1, 512, 0, stream>>>(hist, loss, out);
}

// Round 2
// 435.768 us; speedup vs baseline: 1.5414x; 1.5414x over previous
//
#include <hip/hip_runtime.h>

#define B_ 16
#define D_ 64
#define T_ 4096
#define K_ 512
#define N_ (B_*T_)        // 65536 vectors
#define Q_ (B_*D_*T_)     // 4194304 quantized elements
#define ENC_OFF ((size_t)(2 + Q_))  // encodings start in d_out

// ws layout (bytes) — total ~528 KB (same footprint as round 1)
#define WS_LOSS    0        // double
#define WS_HIST    8        // int[512]
#define WS_AMB_CNT 2056     // int
#define WS_NE      2064     // float[512]
#define WS_IDX     4352     // int[65536]
#define WS_AMB     266496   // int[65536]

// scratch carved from the encodings output region (consumed BEFORE k4_zero):
//   xT   @ enc+0        : float[65536*64]  (16 MB) transposed input rows
//   pmm  @ enc+4194304  : float2[8*65536]  (8 MB)  per-(wave,row) top-2 scores
//   pidx @ enc+6291456  : int[8*65536]     (2 MB)  per-(wave,row) argmin
#define SCR_PMM  4194304
#define SCR_PIDX 6291456

// ---------------- K0: init ws (hist=0, counters=0, ne[k] = ||e_k||^2) -------
__global__ __launch_bounds__(512) void k0_init(const float* __restrict__ cb,
                                               float* __restrict__ ne,
                                               int* __restrict__ hist,
                                               int* __restrict__ amb_cnt,
                                               double* __restrict__ loss) {
    int k = threadIdx.x;
    float s = 0.f;
#pragma unroll
    for (int d = 0; d < 64; ++d) { float c = cb[k*64 + d]; s = fmaf(c, c, s); }
    ne[k] = s;
    hist[k] = 0;
    if (k == 0) { *amb_cnt = 0; *loss = 0.0; }
}

// ---------------- K_T: transpose [B,D,T] -> xT[N][64] (contiguous rows) -----
__global__ __launch_bounds__(256) void k_t(const float* __restrict__ in,
                                           float* __restrict__ xT) {
    __shared__ float tile[64][65];
    int b = blockIdx.y;
    int t0 = blockIdx.x * 64;
    int tt = threadIdx.x & 63;
    int q  = threadIdx.x >> 6;       // 0..3
#pragma unroll
    for (int i = 0; i < 16; ++i) {
        int d = q * 16 + i;
        tile[d][tt] = in[(size_t)b * D_ * T_ + (size_t)d * T_ + t0 + tt];
    }
    __syncthreads();
    int d2 = threadIdx.x & 63;
#pragma unroll
    for (int i = 0; i < 16; ++i) {
        int r = q * 16 + i;
        xT[((size_t)b * T_ + t0 + r) * 64 + d2] = tile[d2][r];
    }
}

// ---------------- K1: codebook-in-VGPR scoring ------------------------------
// Block = 512 threads = 8 waves; wave w owns codes [w*64, w*64+64), lane = code.
// x rows stream through SGPRs (wave-uniform s_load from xT). Scores for a
// 32-row tile go to an XOR-swizzled LDS slice (per-wave private, no barriers),
// then each lane-pair reduces one row to (min1, idx1, min2) partials.
#define TILE_ 32
#define RPB_  128   // rows per block -> grid 512
__global__ __launch_bounds__(512) void k1_score(const float* __restrict__ xT,
                                                const float* __restrict__ cb,
                                                const float* __restrict__ ne,
                                                float2* __restrict__ pmm,
                                                int* __restrict__ pidx) {
    __shared__ float sc[8 * 64 * 32];   // 64 KB: [wave][code][row^swz]
    int w    = threadIdx.x >> 6;
    int lane = threadIdx.x & 63;
    int k    = (w << 6) + lane;         // this lane's code
    int l31  = lane & 31;

    // codebook row -> registers (one-time, L2-hot)
    float c[64];
    const float4* cbr = (const float4*)(cb + (size_t)k * 64);
#pragma unroll
    for (int q = 0; q < 16; ++q) {
        float4 v = cbr[q];
        c[4*q+0] = v.x; c[4*q+1] = v.y; c[4*q+2] = v.z; c[4*q+3] = v.w;
    }
    float nel = ne[k];

    int row_base = blockIdx.x * RPB_;
    float* mysc = sc + ((w << 6) + lane) * 32;      // phase-1 write base
    for (int tb = 0; tb < RPB_; tb += TILE_) {
        int row0 = row_base + tb;
        // phase 1: scores for 32 rows (x via wave-uniform s_load)
        for (int r = 0; r < TILE_; ++r) {
            const float* xr = xT + (size_t)(row0 + r) * 64;
            float a0 = 0.f, a1 = 0.f, a2 = 0.f, a3 = 0.f;
#pragma unroll
            for (int d = 0; d < 64; d += 4) {
                a0 = fmaf(xr[d+0], c[d+0], a0);
                a1 = fmaf(xr[d+1], c[d+1], a1);
                a2 = fmaf(xr[d+2], c[d+2], a2);
                a3 = fmaf(xr[d+3], c[d+3], a3);
            }
            mysc[r ^ l31] = fmaf(-2.f, (a0 + a1) + (a2 + a3), nel);
        }
        // phase 2: lane (h,rr) reduces row rr over codes h*32..h*32+31
        int h = lane >> 5, rr = lane & 31;
        float m1 = 3.4e38f, m2 = 3.4e38f; int i1 = 0;
#pragma unroll
        for (int j = 0; j < 32; ++j) {
            int cc = (h << 5) + j;
            float s = sc[(((w << 6) + cc) << 5) + (rr ^ j)];
            bool lt = s < m1;
            m2 = lt ? m1 : fminf(m2, s);
            i1 = lt ? ((w << 6) + cc) : i1;
            m1 = lt ? s : m1;
        }
        // merge halves (h=0 holds lower code indices; tie -> lower index)
        float om1 = __shfl_xor(m1, 32);
        float om2 = __shfl_xor(m2, 32);
        int   oi1 = __shfl_xor(i1, 32);
        float nm2 = fminf(fmaxf(m1, om1), fminf(m2, om2));
        bool ow = (om1 < m1) || (om1 == m1 && oi1 < i1);
        float nm1 = ow ? om1 : m1;
        int   ni1 = ow ? oi1 : i1;
        if (h == 0) {
            size_t p = (size_t)w * N_ + row0 + rr;
            float2 mm; mm.x = nm1; mm.y = nm2;
            pmm[p] = mm;
            pidx[p] = ni1;
        }
    }
}

// ---------------- K1b: merge 8 wave-partials per row ------------------------
__global__ __launch_bounds__(256) void k1b_combine(const float2* __restrict__ pmm,
                                                   const int* __restrict__ pidx,
                                                   int* __restrict__ idx_out,
                                                   int* __restrict__ amb,
                                                   int* __restrict__ amb_cnt) {
    int n = blockIdx.x * 256 + threadIdx.x;
    float m1 = 3.4e38f, m2 = 3.4e38f; int i1 = 0;
#pragma unroll
    for (int w = 0; w < 8; ++w) {
        float2 p = pmm[(size_t)w * N_ + n];
        int pi = pidx[(size_t)w * N_ + n];
        if (p.x < m1) { m2 = fminf(m1, p.y); i1 = pi; m1 = p.x; }
        else          { m2 = fminf(m2, p.x); }
    }
    idx_out[n] = i1;
    if (m2 - m1 < 1e-4f) {
        int p = atomicAdd(amb_cnt, 1);
        amb[p] = n;
    }
}

// ---------------- K2: exact f64 refine for ambiguous rows -------------------
__global__ __launch_bounds__(64) void k2_refine(const float* __restrict__ xT,
                                                const float* __restrict__ cb,
                                                const int* __restrict__ amb,
                                                const int* __restrict__ amb_cnt,
                                                int* __restrict__ idx_out) {
    int cnt = *amb_cnt;
    int lane = threadIdx.x;
    for (int i = blockIdx.x; i < cnt; i += gridDim.x) {
        int n = amb[i];
        const float* xp = xT + (size_t)n * 64;
        double best = 1e300; int bidx = 0;
#pragma unroll
        for (int j = 0; j < 8; ++j) {
            int k = j * 64 + lane;
            const float* c = cb + k * 64;
            double dot = 0.0, nrm = 0.0;
            for (int d = 0; d < 64; ++d) {
                double cd = (double)c[d];
                dot = fma(cd, (double)xp[d], dot);
                nrm = fma(cd, cd, nrm);
            }
            double score = nrm - 2.0 * dot;
            if (score < best) { best = score; bidx = k; }  // j asc => k asc per lane
        }
        for (int off = 32; off > 0; off >>= 1) {
            double ob = __shfl_down(best, off);
            int oi = __shfl_down(bidx, off);
            if (ob < best || (ob == best && oi < bidx)) { best = ob; bidx = oi; }
        }
        if (lane == 0) idx_out[n] = bidx;
    }
}

// ---------------- K4: zero-fill encodings (float2: base only 8B-aligned) ----
__global__ void k4_zero(float2* __restrict__ enc2) {
    size_t i = (size_t)blockIdx.x * blockDim.x + threadIdx.x;
    size_t stride = (size_t)gridDim.x * blockDim.x;
    const size_t n2 = (size_t)N_ * K_ / 2;  // 16777216
    float2 z; z.x = 0.f; z.y = 0.f;
    for (size_t j = i; j < n2; j += stride) enc2[j] = z;
}

// ---------------- K3: quantized output, loss partials, hist, one-hot ones ---
__global__ __launch_bounds__(256) void k3_outputs(const float* __restrict__ in,
                                                  const float* __restrict__ cb,
                                                  const int* __restrict__ idx_arr,
                                                  float* __restrict__ out,
                                                  int* __restrict__ hist,
                                                  double* __restrict__ loss) {
    int n = blockIdx.x * 256 + threadIdx.x;
    int b = n >> 12, t = n & (T_ - 1);
    const float* xp = in + (size_t)b * D_ * T_ + t;
    float* qp = out + 1 + (size_t)b * D_ * T_ + t;
    int idx = idx_arr[n];
    const float4* c4 = (const float4*)(cb + idx * 64);

    float lsum = 0.f;
#pragma unroll
    for (int d4 = 0; d4 < 16; ++d4) {
        float4 q = c4[d4];
        float qe[4] = {q.x, q.y, q.z, q.w};
#pragma unroll
        for (int e = 0; e < 4; ++e) {
            int d = d4 * 4 + e;
            float xv = xp[d * T_];
            float diff = qe[e] - xv;
            lsum = fmaf(diff, diff, lsum);
            qp[d * T_] = xv + diff;               // straight-through: x + (q - x)
        }
    }

    atomicAdd(&hist[idx], 1);
    out[ENC_OFF + (size_t)n * K_ + idx] = 1.0f;

#pragma unroll
    for (int off = 32; off > 0; off >>= 1) lsum += __shfl_down(lsum, off);
    __shared__ float wsum[4];
    int wid = threadIdx.x >> 6;
    if ((threadIdx.x & 63) == 0) wsum[wid] = lsum;
    __syncthreads();
    if (threadIdx.x == 0) {
        double s = (double)wsum[0] + (double)wsum[1] + (double)wsum[2] + (double)wsum[3];
        atomicAdd(loss, s);
    }
}

// ---------------- K6: finalize loss + perplexity ----------------------------
__global__ __launch_bounds__(512) void k6_final(const int* __restrict__ hist,
                                                const double* __restrict__ loss,
                                                float* __restrict__ out) {
    __shared__ double sh[512];
    int k = threadIdx.x;
    double p = (double)hist[k] / (double)N_;
    sh[k] = p * log(p + 1e-10);
    __syncthreads();
    for (int s = 256; s > 0; s >>= 1) {
        if (k < s) sh[k] += sh[k + s];
        __syncthreads();
    }
    if (k == 0) {
        out[1 + Q_] = (float)exp(-sh[0]);
        out[0] = (float)(1.25 * (*loss) / (double)Q_);
    }
}

extern "C" void kernel_launch(void* const* d_in, const int* in_sizes, int n_in,
                              void* d_out, int out_size, void* d_ws, size_t ws_size,
                              hipStream_t stream) {
    const float* in = (const float*)d_in[0];   // [16, 64, 4096] fp32
    const float* cb = (const float*)d_in[1];   // [512, 64] fp32
    float* out = (float*)d_out;
    char* ws = (char*)d_ws;

    double* loss  = (double*)(ws + WS_LOSS);
    int* hist     = (int*)(ws + WS_HIST);
    int* amb_cnt  = (int*)(ws + WS_AMB_CNT);
    float* ne     = (float*)(ws + WS_NE);
    int* idx      = (int*)(ws + WS_IDX);
    int* amb      = (int*)(ws + WS_AMB);

    float*  enc  = out + ENC_OFF;
    float*  xT   = enc;                          // 16 MB scratch in enc region
    float2* pmm  = (float2*)(enc + SCR_PMM);
    int*    pidx = (int*)(enc + SCR_PIDX);

    k0_init<<<1, 512, 0, stream>>>(cb, ne, hist, amb_cnt, loss);
    {
        dim3 g(T_ / 64, B_);
        k_t<<<g, 256, 0, stream>>>(in, xT);
    }
    k1_score<<<N_ / RPB_, 512, 0, stream>>>(xT, cb, ne, pmm, pidx);
    k1b_combine<<<N_ / 256, 256, 0, stream>>>(pmm, pidx, idx, amb, amb_cnt);
    k2_refine<<<512, 64, 0, stream>>>(xT, cb, amb, amb_cnt, idx);
    // scratch in enc region no longer needed past this point
    k4_zero<<<2048, 256, 0, stream>>>((float2*)enc);
    k3_outputs<<<N_ / 256, 256, 0, stream>>>(in, cb, idx, out, hist, loss);
    k6_final<<<1, 512, 0, stream>>>(hist, loss, out);
}

// Round 3
// 254.353 us; speedup vs baseline: 2.6408x; 1.7132x over previous
//
#include <hip/hip_runtime.h>

#define B_ 16
#define D_ 64
#define T_ 4096
#define K_ 512
#define N_ (B_*T_)        // 65536 vectors
#define Q_ (B_*D_*T_)     // 4194304 quantized elements
#define ENC_OFF ((size_t)(2 + Q_))  // encodings start in d_out

// ws layout (bytes) — ~650 KB
#define WS_LOSS    0        // double
#define WS_HIST    8        // int[512]
#define WS_AMB_CNT 2056     // int
#define WS_NE      2064     // float[512]
#define WS_IDX     4352     // int[65536]
#define WS_AMB     266496   // int[65536]
#define WS_CBH     528640   // bf16x8[32*2*64]  (64 KB) codebook hi frags
#define WS_CBL     594176   // bf16x8[32*2*64]  (64 KB) codebook lo frags

typedef __bf16 bf16x8 __attribute__((ext_vector_type(8)));
typedef float  f32x4  __attribute__((ext_vector_type(4)));

#define MARGIN_ 2.5e-6f

// x fragments: [rt(4096)][ks(2)][lane(64)] bf16x8 -> 8 MB each, stored in the
// encodings output region (k4_onehot overwrites it afterwards).
#define XFRAGS_ ((size_t)4096 * 2 * 64)

// ---------------- K0: init + ne + codebook hi/lo B-fragments ----------------
__global__ __launch_bounds__(512) void k0_init(const float* __restrict__ cb,
                                               float* __restrict__ ne,
                                               int* __restrict__ hist,
                                               int* __restrict__ amb_cnt,
                                               double* __restrict__ loss,
                                               bf16x8* __restrict__ cbh,
                                               bf16x8* __restrict__ cbl) {
    int tid = threadIdx.x;
    float s = 0.f;
#pragma unroll
    for (int d = 0; d < 64; ++d) { float c = cb[tid*64 + d]; s = fmaf(c, c, s); }
    ne[tid] = s;
    hist[tid] = 0;
    if (tid == 0) { *amb_cnt = 0; *loss = 0.0; }

    // B-operand frags: element (ct,ks,lane,j) = cb[ct*16 + (lane&15)][ks*32 + (lane>>4)*8 + j]
    int lane = tid & 63;
    int g0   = tid >> 6;            // 0..7
#pragma unroll
    for (int g = 0; g < 8; ++g) {
        int ctks = g * 8 + g0;      // 0..63
        int ct = ctks >> 1, ks = ctks & 1;
        int code  = ct * 16 + (lane & 15);
        int dbase = ks * 32 + ((lane >> 4) << 3);
        bf16x8 h, l;
#pragma unroll
        for (int j = 0; j < 8; ++j) {
            float v = cb[code * 64 + dbase + j];
            __bf16 hv = (__bf16)v;
            __bf16 lv = (__bf16)(v - (float)hv);
            h[j] = hv; l[j] = lv;
        }
        cbh[(ct * 2 + ks) * 64 + lane] = h;
        cbl[(ct * 2 + ks) * 64 + lane] = l;
    }
}

// ---------------- KA: x hi/lo A-fragments (transpose via LDS) ---------------
// Block = 256 thr = 64 rows (4 row-tiles of 16). A[m=lane&15][k=(lane>>4)*8+j].
__global__ __launch_bounds__(256) void kA_prep(const float* __restrict__ in,
                                               bf16x8* __restrict__ xh,
                                               bf16x8* __restrict__ xl) {
    __shared__ float X[64][65];
    int n0 = blockIdx.x * 64;
    int b  = n0 >> 12, t0 = n0 & (T_ - 1);
    int g = threadIdx.x >> 6, lane = threadIdx.x & 63;
#pragma unroll
    for (int i = 0; i < 16; ++i) {
        int d = g * 16 + i;
        X[d][lane] = in[((size_t)b * 64 + d) * T_ + t0 + lane];
    }
    __syncthreads();
    int rt_g = blockIdx.x * 4 + g;
    int m = lane & 15, q = lane >> 4;
#pragma unroll
    for (int ks = 0; ks < 2; ++ks) {
        bf16x8 h, l;
#pragma unroll
        for (int j = 0; j < 8; ++j) {
            float v = X[ks * 32 + q * 8 + j][g * 16 + m];
            __bf16 hv = (__bf16)v;
            __bf16 lv = (__bf16)(v - (float)hv);
            h[j] = hv; l[j] = lv;
        }
        xh[((size_t)rt_g * 2 + ks) * 64 + lane] = h;
        xl[((size_t)rt_g * 2 + ks) * 64 + lane] = l;
    }
}

// ---------------- K1: MFMA bf16x(h+l)^2 scoring + top-2 ---------------------
// Wave = 32 rows (2 row-tiles); block = 4 waves = 128 rows; grid = 512.
__global__ __launch_bounds__(256) void k1_score(const bf16x8* __restrict__ xh,
                                                const bf16x8* __restrict__ xl,
                                                const bf16x8* __restrict__ cbh,
                                                const bf16x8* __restrict__ cbl,
                                                const float* __restrict__ ne,
                                                int* __restrict__ idx_out,
                                                int* __restrict__ amb,
                                                int* __restrict__ amb_cnt) {
    __shared__ float ne_s[512];
    int tid = threadIdx.x;
    ne_s[tid] = ne[tid];
    ne_s[tid + 256] = ne[tid + 256];
    __syncthreads();

    int w = tid >> 6, lane = tid & 63;
    int rt0 = blockIdx.x * 8 + w * 2;
    int col = lane & 15, q = lane >> 4;

    bf16x8 Ah[2][2], Al[2][2];
#pragma unroll
    for (int r = 0; r < 2; ++r)
#pragma unroll
        for (int ks = 0; ks < 2; ++ks) {
            Ah[r][ks] = xh[((size_t)(rt0 + r) * 2 + ks) * 64 + lane];
            Al[r][ks] = xl[((size_t)(rt0 + r) * 2 + ks) * 64 + lane];
        }

    float m1[2][4], m2[2][4]; int i1[2][4];
#pragma unroll
    for (int r = 0; r < 2; ++r)
#pragma unroll
        for (int e = 0; e < 4; ++e) { m1[r][e] = 3.4e38f; m2[r][e] = 3.4e38f; i1[r][e] = 0; }

    for (int ct = 0; ct < 32; ++ct) {
        bf16x8 Bh0 = cbh[(ct * 2 + 0) * 64 + lane];
        bf16x8 Bh1 = cbh[(ct * 2 + 1) * 64 + lane];
        bf16x8 Bl0 = cbl[(ct * 2 + 0) * 64 + lane];
        bf16x8 Bl1 = cbl[(ct * 2 + 1) * 64 + lane];
        float nev = ne_s[ct * 16 + col];
        int code = ct * 16 + col;
#pragma unroll
        for (int r = 0; r < 2; ++r) {
            f32x4 acc = {0.f, 0.f, 0.f, 0.f};
            acc = __builtin_amdgcn_mfma_f32_16x16x32_bf16(Ah[r][0], Bh0, acc, 0, 0, 0);
            acc = __builtin_amdgcn_mfma_f32_16x16x32_bf16(Ah[r][1], Bh1, acc, 0, 0, 0);
            acc = __builtin_amdgcn_mfma_f32_16x16x32_bf16(Ah[r][0], Bl0, acc, 0, 0, 0);
            acc = __builtin_amdgcn_mfma_f32_16x16x32_bf16(Al[r][0], Bh0, acc, 0, 0, 0);
            acc = __builtin_amdgcn_mfma_f32_16x16x32_bf16(Ah[r][1], Bl1, acc, 0, 0, 0);
            acc = __builtin_amdgcn_mfma_f32_16x16x32_bf16(Al[r][1], Bh1, acc, 0, 0, 0);
            acc = __builtin_amdgcn_mfma_f32_16x16x32_bf16(Al[r][0], Bl0, acc, 0, 0, 0);
            acc = __builtin_amdgcn_mfma_f32_16x16x32_bf16(Al[r][1], Bl1, acc, 0, 0, 0);
#pragma unroll
            for (int e = 0; e < 4; ++e) {
                float sc = fmaf(-2.f, acc[e], nev);   // ||e||^2 - 2 x.e
                bool lt = sc < m1[r][e];
                m2[r][e] = lt ? m1[r][e] : fminf(m2[r][e], sc);
                i1[r][e] = lt ? code : i1[r][e];
                m1[r][e] = lt ? sc : m1[r][e];
            }
        }
    }

    // merge top-2 across the 16 lanes (same q) holding this row's columns
#pragma unroll
    for (int r = 0; r < 2; ++r)
#pragma unroll
        for (int e = 0; e < 4; ++e) {
            float a1 = m1[r][e], a2 = m2[r][e]; int ai = i1[r][e];
#pragma unroll
            for (int off = 1; off < 16; off <<= 1) {
                float o1 = __shfl_xor(a1, off);
                float o2 = __shfl_xor(a2, off);
                int   oi = __shfl_xor(ai, off);
                float nn2 = fminf(fmaxf(a1, o1), fminf(a2, o2));
                bool tk = (o1 < a1) || (o1 == a1 && oi < ai);  // tie -> lower index
                a1 = tk ? o1 : a1; ai = tk ? oi : ai; a2 = nn2;
            }
            if (col == 0) {
                int n = (rt0 + r) * 16 + q * 4 + e;
                idx_out[n] = ai;
                if (a2 - a1 < MARGIN_) { int p = atomicAdd(amb_cnt, 1); amb[p] = n; }
            }
        }
}

// ---------------- K2: exact f64 refine for ambiguous rows -------------------
__global__ __launch_bounds__(64) void k2_refine(const float* __restrict__ in,
                                                const float* __restrict__ cb,
                                                const int* __restrict__ amb,
                                                const int* __restrict__ amb_cnt,
                                                int* __restrict__ idx_out) {
    int cnt = *amb_cnt;
    int lane = threadIdx.x;
    for (int i = blockIdx.x; i < cnt; i += gridDim.x) {
        int n = amb[i];
        int b = n >> 12, t = n & (T_ - 1);
        const float* xp = in + (size_t)b * D_ * T_ + t;
        double best = 1e300; int bidx = 0;
#pragma unroll
        for (int j = 0; j < 8; ++j) {
            int k = j * 64 + lane;
            const float* c = cb + k * 64;
            double dot = 0.0, nrm = 0.0;
            for (int d = 0; d < 64; ++d) {
                double cd = (double)c[d];
                dot = fma(cd, (double)xp[d * T_], dot);
                nrm = fma(cd, cd, nrm);
            }
            double score = nrm - 2.0 * dot;
            if (score < best) { best = score; bidx = k; }
        }
        for (int off = 32; off > 0; off >>= 1) {
            double ob = __shfl_down(best, off);
            int oi = __shfl_down(bidx, off);
            if (ob < best || (ob == best && oi < bidx)) { best = ob; bidx = oi; }
        }
        if (lane == 0) idx_out[n] = bidx;
    }
}

// ---------------- K4: write one-hot encodings (zeros + 1.0), coalesced ------
__global__ __launch_bounds__(256) void k4_onehot(const int* __restrict__ idx_arr,
                                                 float2* __restrict__ enc2) {
    int t = threadIdx.x;
#pragma unroll 4
    for (int i = 0; i < 64; ++i) {
        int row = blockIdx.x * 64 + i;
        int id = idx_arr[row];                     // wave-uniform -> s_load
        float2 v;
        v.x = ((id >> 1) == t && (id & 1) == 0) ? 1.f : 0.f;
        v.y = ((id >> 1) == t && (id & 1) == 1) ? 1.f : 0.f;
        enc2[(size_t)row * 256 + t] = v;
    }
}

// ---------------- K3: quantized output, loss partials, hist -----------------
__global__ __launch_bounds__(256) void k3_outputs(const float* __restrict__ in,
                                                  const float* __restrict__ cb,
                                                  const int* __restrict__ idx_arr,
                                                  float* __restrict__ out,
                                                  int* __restrict__ hist,
                                                  double* __restrict__ loss) {
    int n = blockIdx.x * 256 + threadIdx.x;
    int b = n >> 12, t = n & (T_ - 1);
    const float* xp = in + (size_t)b * D_ * T_ + t;
    float* qp = out + 1 + (size_t)b * D_ * T_ + t;
    int idx = idx_arr[n];
    const float4* c4 = (const float4*)(cb + idx * 64);

    float lsum = 0.f;
#pragma unroll
    for (int d4 = 0; d4 < 16; ++d4) {
        float4 qv = c4[d4];
        float qe[4] = {qv.x, qv.y, qv.z, qv.w};
#pragma unroll
        for (int e = 0; e < 4; ++e) {
            int d = d4 * 4 + e;
            float xv = xp[d * T_];
            float diff = qe[e] - xv;
            lsum = fmaf(diff, diff, lsum);
            qp[d * T_] = xv + diff;               // straight-through: x + (q - x)
        }
    }

    atomicAdd(&hist[idx], 1);

#pragma unroll
    for (int off = 32; off > 0; off >>= 1) lsum += __shfl_down(lsum, off);
    __shared__ float wsum[4];
    int wid = threadIdx.x >> 6;
    if ((threadIdx.x & 63) == 0) wsum[wid] = lsum;
    __syncthreads();
    if (threadIdx.x == 0) {
        double s = (double)wsum[0] + (double)wsum[1] + (double)wsum[2] + (double)wsum[3];
        atomicAdd(loss, s);
    }
}

// ---------------- K6: finalize loss + perplexity ----------------------------
__global__ __launch_bounds__(512) void k6_final(const int* __restrict__ hist,
                                                const double* __restrict__ loss,
                                                float* __restrict__ out) {
    __shared__ double sh[512];
    int k = threadIdx.x;
    double p = (double)hist[k] / (double)N_;
    sh[k] = p * log(p + 1e-10);
    __syncthreads();
    for (int s = 256; s > 0; s >>= 1) {
        if (k < s) sh[k] += sh[k + s];
        __syncthreads();
    }
    if (k == 0) {
        out[1 + Q_] = (float)exp(-sh[0]);
        out[0] = (float)(1.25 * (*loss) / (double)Q_);
    }
}

extern "C" void kernel_launch(void* const* d_in, const int* in_sizes, int n_in,
                              void* d_out, int out_size, void* d_ws, size_t ws_size,
                              hipStream_t stream) {
    const float* in = (const float*)d_in[0];   // [16, 64, 4096] fp32
    const float* cb = (const float*)d_in[1];   // [512, 64] fp32
    float* out = (float*)d_out;
    char* ws = (char*)d_ws;

    double* loss  = (double*)(ws + WS_LOSS);
    int* hist     = (int*)(ws + WS_HIST);
    int* amb_cnt  = (int*)(ws + WS_AMB_CNT);
    float* ne     = (float*)(ws + WS_NE);
    int* idx      = (int*)(ws + WS_IDX);
    int* amb      = (int*)(ws + WS_AMB);
    bf16x8* cbh   = (bf16x8*)(ws + WS_CBH);
    bf16x8* cbl   = (bf16x8*)(ws + WS_CBL);

    float* enc = out + ENC_OFF;
    // x fragments live in the encodings region (16B-aligned at enc+2);
    // k4_onehot overwrites this region after k1/k2 are done with it.
    bf16x8* xh = (bf16x8*)(enc + 2);
    bf16x8* xl = xh + XFRAGS_;

    k0_init<<<1, 512, 0, stream>>>(cb, ne, hist, amb_cnt, loss, cbh, cbl);
    kA_prep<<<N_ / 64, 256, 0, stream>>>(in, xh, xl);
    k1_score<<<512, 256, 0, stream>>>(xh, xl, cbh, cbl, ne, idx, amb, amb_cnt);
    k2_refine<<<512, 64, 0, stream>>>(in, cb, amb, amb_cnt, idx);
    k4_onehot<<<N_ / 64, 256, 0, stream>>>(idx, (float2*)enc);
    k3_outputs<<<N_ / 256, 256, 0, stream>>>(in, cb, idx, out, hist, loss);
    k6_final<<<1, 512, 0, stream>>>(hist, loss, out);
}

// Round 4
// 231.542 us; speedup vs baseline: 2.9010x; 1.0985x over previous
//
#include <hip/hip_runtime.h>

#define B_ 16
#define D_ 64
#define T_ 4096
#define K_ 512
#define N_ (B_*T_)        // 65536 vectors
#define Q_ (B_*D_*T_)     // 4194304 quantized elements
#define ENC_OFF ((size_t)(2 + Q_))  // encodings start in d_out

// ws layout (bytes) — ~660 KB
#define WS_LOSS    0        // double
#define WS_HIST    8        // int[512]
#define WS_AMB_CNT 2056     // int
#define WS_NE      2064     // float[512]
#define WS_IDX     4352     // int[65536]
#define WS_AMB     266496   // int[65536]
#define WS_CBH     528640   // bf16x8[32*2*64]  (64 KB) codebook hi frags
#define WS_CBL     594176   // bf16x8[32*2*64]  (64 KB) codebook lo frags

typedef __bf16 bf16x8 __attribute__((ext_vector_type(8)));
typedef float  f32x4  __attribute__((ext_vector_type(4)));

#define MARGIN_ 2.5e-6f

// ---------------- K0: init + ne + codebook hi/lo B-fragments ----------------
__global__ __launch_bounds__(512) void k0_init(const float* __restrict__ cb,
                                               float* __restrict__ ne,
                                               int* __restrict__ hist,
                                               int* __restrict__ amb_cnt,
                                               double* __restrict__ loss,
                                               bf16x8* __restrict__ cbh,
                                               bf16x8* __restrict__ cbl) {
    int tid = threadIdx.x;
    float s = 0.f;
#pragma unroll
    for (int d = 0; d < 64; ++d) { float c = cb[tid*64 + d]; s = fmaf(c, c, s); }
    ne[tid] = s;
    hist[tid] = 0;
    if (tid == 0) { *amb_cnt = 0; *loss = 0.0; }

    // B-frag element (ct,ks,lane,j) = cb[ct*16 + (lane&15)][ks*32 + (lane>>4)*8 + j]
    int lane = tid & 63;
    int g0   = tid >> 6;            // 0..7
#pragma unroll
    for (int g = 0; g < 8; ++g) {
        int ctks = g * 8 + g0;      // 0..63
        int ct = ctks >> 1, ks = ctks & 1;
        int code  = ct * 16 + (lane & 15);
        int dbase = ks * 32 + ((lane >> 4) << 3);
        bf16x8 h, l;
#pragma unroll
        for (int j = 0; j < 8; ++j) {
            float v = cb[code * 64 + dbase + j];
            __bf16 hv = (__bf16)v;
            __bf16 lv = (__bf16)(v - (float)hv);
            h[j] = hv; l[j] = lv;
        }
        cbh[(ct * 2 + ks) * 64 + lane] = h;
        cbl[(ct * 2 + ks) * 64 + lane] = l;
    }
}

// ---------------- K1: fused stage+frag+MFMA scoring + top-2 -----------------
// Block = 256 thr = 4 waves = 128 rows (8 row-tiles); grid = 512.
// Stages x-tile [64 d][128 t] in LDS, builds hi/lo bf16 A-frags in registers,
// then streams codebook B-frags (ws, L2-hot) through 8 MFMAs per 16x16 tile.
__global__ __launch_bounds__(256) void k1_score(const float* __restrict__ in,
                                                const bf16x8* __restrict__ cbh,
                                                const bf16x8* __restrict__ cbl,
                                                const float* __restrict__ ne,
                                                int* __restrict__ idx_out,
                                                int* __restrict__ amb,
                                                int* __restrict__ amb_cnt) {
    __shared__ float X[64][129];     // 33 KB; frag reads <=2-way bank alias (free)
    __shared__ float ne_s[512];
    int tid = threadIdx.x;
    int n0 = blockIdx.x * 128;
    int b  = n0 >> 12, t0 = n0 & (T_ - 1);

    { // stage: 8192 floats, 32 per thread, coalesced
        int tl = tid & 127, dg = tid >> 7;
#pragma unroll
        for (int i = 0; i < 32; ++i) {
            int d = dg * 32 + i;
            X[d][tl] = in[((size_t)b * 64 + d) * T_ + t0 + tl];
        }
    }
    ne_s[tid] = ne[tid];
    ne_s[tid + 256] = ne[tid + 256];
    __syncthreads();

    int w = tid >> 6, lane = tid & 63;
    int col = lane & 15, q = lane >> 4;

    // A-frags for this wave's 2 row-tiles: A[m][k=ks*32+q*8+j] = x_row[d]
    bf16x8 Ah[2][2], Al[2][2];
#pragma unroll
    for (int r = 0; r < 2; ++r) {
        int rl = (w * 2 + r) * 16 + col;      // local row
#pragma unroll
        for (int ks = 0; ks < 2; ++ks) {
            bf16x8 h, l;
#pragma unroll
            for (int j = 0; j < 8; ++j) {
                float v = X[ks * 32 + q * 8 + j][rl];
                __bf16 hv = (__bf16)v;
                __bf16 lv = (__bf16)(v - (float)hv);
                h[j] = hv; l[j] = lv;
            }
            Ah[r][ks] = h; Al[r][ks] = l;
        }
    }

    int rt0 = blockIdx.x * 8 + w * 2;         // global row-tile base
    float m1[2][4], m2[2][4]; int i1[2][4];
#pragma unroll
    for (int r = 0; r < 2; ++r)
#pragma unroll
        for (int e = 0; e < 4; ++e) { m1[r][e] = 3.4e38f; m2[r][e] = 3.4e38f; i1[r][e] = 0; }

    for (int ct = 0; ct < 32; ++ct) {
        bf16x8 Bh0 = cbh[(ct * 2 + 0) * 64 + lane];
        bf16x8 Bh1 = cbh[(ct * 2 + 1) * 64 + lane];
        bf16x8 Bl0 = cbl[(ct * 2 + 0) * 64 + lane];
        bf16x8 Bl1 = cbl[(ct * 2 + 1) * 64 + lane];
        float nev = ne_s[ct * 16 + col];
        int code = ct * 16 + col;
#pragma unroll
        for (int r = 0; r < 2; ++r) {
            f32x4 acc = {0.f, 0.f, 0.f, 0.f};
            acc = __builtin_amdgcn_mfma_f32_16x16x32_bf16(Ah[r][0], Bh0, acc, 0, 0, 0);
            acc = __builtin_amdgcn_mfma_f32_16x16x32_bf16(Ah[r][1], Bh1, acc, 0, 0, 0);
            acc = __builtin_amdgcn_mfma_f32_16x16x32_bf16(Ah[r][0], Bl0, acc, 0, 0, 0);
            acc = __builtin_amdgcn_mfma_f32_16x16x32_bf16(Al[r][0], Bh0, acc, 0, 0, 0);
            acc = __builtin_amdgcn_mfma_f32_16x16x32_bf16(Ah[r][1], Bl1, acc, 0, 0, 0);
            acc = __builtin_amdgcn_mfma_f32_16x16x32_bf16(Al[r][1], Bh1, acc, 0, 0, 0);
            acc = __builtin_amdgcn_mfma_f32_16x16x32_bf16(Al[r][0], Bl0, acc, 0, 0, 0);
            acc = __builtin_amdgcn_mfma_f32_16x16x32_bf16(Al[r][1], Bl1, acc, 0, 0, 0);
#pragma unroll
            for (int e = 0; e < 4; ++e) {
                float sc = fmaf(-2.f, acc[e], nev);   // ||e||^2 - 2 x.e
                bool lt = sc < m1[r][e];
                m2[r][e] = lt ? m1[r][e] : fminf(m2[r][e], sc);
                i1[r][e] = lt ? code : i1[r][e];
                m1[r][e] = lt ? sc : m1[r][e];
            }
        }
    }

    // merge top-2 across the 16 lanes (same q) holding this row's columns
#pragma unroll
    for (int r = 0; r < 2; ++r)
#pragma unroll
        for (int e = 0; e < 4; ++e) {
            float a1 = m1[r][e], a2 = m2[r][e]; int ai = i1[r][e];
#pragma unroll
            for (int off = 1; off < 16; off <<= 1) {
                float o1 = __shfl_xor(a1, off);
                float o2 = __shfl_xor(a2, off);
                int   oi = __shfl_xor(ai, off);
                float nn2 = fminf(fmaxf(a1, o1), fminf(a2, o2));
                bool tk = (o1 < a1) || (o1 == a1 && oi < ai);  // tie -> lower index
                a1 = tk ? o1 : a1; ai = tk ? oi : ai; a2 = nn2;
            }
            if (col == 0) {
                int n = (rt0 + r) * 16 + q * 4 + e;
                idx_out[n] = ai;
                if (a2 - a1 < MARGIN_) { int p = atomicAdd(amb_cnt, 1); amb[p] = n; }
            }
        }
}

// ---------------- K2: exact f64 refine for ambiguous rows -------------------
__global__ __launch_bounds__(64) void k2_refine(const float* __restrict__ in,
                                                const float* __restrict__ cb,
                                                const int* __restrict__ amb,
                                                const int* __restrict__ amb_cnt,
                                                int* __restrict__ idx_out) {
    int cnt = *amb_cnt;
    int lane = threadIdx.x;
    for (int i = blockIdx.x; i < cnt; i += gridDim.x) {
        int n = amb[i];
        int b = n >> 12, t = n & (T_ - 1);
        const float* xp = in + (size_t)b * D_ * T_ + t;
        double best = 1e300; int bidx = 0;
#pragma unroll
        for (int j = 0; j < 8; ++j) {
            int k = j * 64 + lane;
            const float* c = cb + k * 64;
            double dot = 0.0, nrm = 0.0;
            for (int d = 0; d < 64; ++d) {
                double cd = (double)c[d];
                dot = fma(cd, (double)xp[d * T_], dot);
                nrm = fma(cd, cd, nrm);
            }
            double score = nrm - 2.0 * dot;
            if (score < best) { best = score; bidx = k; }
        }
        for (int off = 32; off > 0; off >>= 1) {
            double ob = __shfl_down(best, off);
            int oi = __shfl_down(bidx, off);
            if (ob < best || (ob == best && oi < bidx)) { best = ob; bidx = oi; }
        }
        if (lane == 0) idx_out[n] = bidx;
    }
}

// ---------------- K34: one-hot + quantized + loss + hist (fused) ------------
// Block = 256 thr, 64 rows; grid = 1024.
__global__ __launch_bounds__(256) void k34_outputs(const float* __restrict__ in,
                                                   const float* __restrict__ cb,
                                                   const int* __restrict__ idx_arr,
                                                   float* __restrict__ out,
                                                   float2* __restrict__ enc2,
                                                   int* __restrict__ hist,
                                                   double* __restrict__ loss) {
    int tid = threadIdx.x;
    int n0 = blockIdx.x * 64;
    int b = n0 >> 12, t0 = n0 & (T_ - 1);

    // --- one-hot rows (coalesced full-row writes, zeros + single 1.0) ---
#pragma unroll 4
    for (int i = 0; i < 64; ++i) {
        int row = n0 + i;
        int id = idx_arr[row];                 // wave-uniform -> s_load
        float2 v;
        v.x = ((id >> 1) == tid && (id & 1) == 0) ? 1.f : 0.f;
        v.y = ((id >> 1) == tid && (id & 1) == 1) ? 1.f : 0.f;
        enc2[(size_t)row * 256 + tid] = v;
    }

    // --- quantized + loss: lane = row (tl), 16 dims per thread ---
    int tl = tid & 63, dg = tid >> 6;
    int n = n0 + tl;
    int idx = idx_arr[n];
    const float4* c4 = (const float4*)(cb + (size_t)idx * 64);
    const float* xp = in + (size_t)b * D_ * T_ + t0 + tl;
    float* qp = out + 1 + (size_t)b * D_ * T_ + t0 + tl;

    float lsum = 0.f;
#pragma unroll
    for (int j = 0; j < 4; ++j) {
        float4 qv = c4[dg * 4 + j];
        float qe[4] = {qv.x, qv.y, qv.z, qv.w};
#pragma unroll
        for (int e = 0; e < 4; ++e) {
            int d = dg * 16 + j * 4 + e;
            float xv = xp[(size_t)d * T_];
            float diff = qe[e] - xv;
            lsum = fmaf(diff, diff, lsum);
            qp[(size_t)d * T_] = xv + diff;    // straight-through: x + (q - x)
        }
    }
    if (tid < 64) atomicAdd(&hist[idx], 1);    // one count per row

#pragma unroll
    for (int off = 32; off > 0; off >>= 1) lsum += __shfl_down(lsum, off);
    __shared__ float wsum[4];
    if ((tid & 63) == 0) wsum[tid >> 6] = lsum;
    __syncthreads();
    if (tid == 0) {
        double s = (double)wsum[0] + (double)wsum[1] + (double)wsum[2] + (double)wsum[3];
        atomicAdd(loss, s);
    }
}

// ---------------- K6: finalize loss + perplexity ----------------------------
__global__ __launch_bounds__(512) void k6_final(const int* __restrict__ hist,
                                                const double* __restrict__ loss,
                                                float* __restrict__ out) {
    __shared__ double sh[512];
    int k = threadIdx.x;
    double p = (double)hist[k] / (double)N_;
    sh[k] = p * log(p + 1e-10);
    __syncthreads();
    for (int s = 256; s > 0; s >>= 1) {
        if (k < s) sh[k] += sh[k + s];
        __syncthreads();
    }
    if (k == 0) {
        out[1 + Q_] = (float)exp(-sh[0]);
        out[0] = (float)(1.25 * (*loss) / (double)Q_);
    }
}

extern "C" void kernel_launch(void* const* d_in, const int* in_sizes, int n_in,
                              void* d_out, int out_size, void* d_ws, size_t ws_size,
                              hipStream_t stream) {
    const float* in = (const float*)d_in[0];   // [16, 64, 4096] fp32
    const float* cb = (const float*)d_in[1];   // [512, 64] fp32
    float* out = (float*)d_out;
    char* ws = (char*)d_ws;

    double* loss  = (double*)(ws + WS_LOSS);
    int* hist     = (int*)(ws + WS_HIST);
    int* amb_cnt  = (int*)(ws + WS_AMB_CNT);
    float* ne     = (float*)(ws + WS_NE);
    int* idx      = (int*)(ws + WS_IDX);
    int* amb      = (int*)(ws + WS_AMB);
    bf16x8* cbh   = (bf16x8*)(ws + WS_CBH);
    bf16x8* cbl   = (bf16x8*)(ws + WS_CBL);

    float2* enc2 = (float2*)(out + ENC_OFF);

    k0_init<<<1, 512, 0, stream>>>(cb, ne, hist, amb_cnt, loss, cbh, cbl);
    k1_score<<<512, 256, 0, stream>>>(in, cbh, cbl, ne, idx, amb, amb_cnt);
    k2_refine<<<512, 64, 0, stream>>>(in, cb, amb, amb_cnt, idx);
    k34_outputs<<<N_ / 64, 256, 0, stream>>>(in, cb, idx, out, enc2, hist, loss);
    k6_final<<<1, 512, 0, stream>>>(hist, loss, out);
}

// Round 5
// 198.828 us; speedup vs baseline: 3.3783x; 1.1645x over previous
//
#include <hip/hip_runtime.h>

#define B_ 16
#define D_ 64
#define T_ 4096
#define K_ 512
#define N_ (B_*T_)        // 65536 vectors
#define Q_ (B_*D_*T_)     // 4194304 quantized elements
#define ENC_OFF ((size_t)(2 + Q_))  // encodings start in d_out

// ws layout (bytes) — ~136 KB
#define WS_LOSS    0        // double
#define WS_HIST    8        // int[512]
#define WS_NE      2064     // float[512]
#define WS_CBH     4608     // bf16x8[32*2*64]  (64 KB) codebook hi frags
#define WS_CBL     70144    // bf16x8[32*2*64]  (64 KB) codebook lo frags

typedef __bf16 bf16x8 __attribute__((ext_vector_type(8)));
typedef float  f32x4  __attribute__((ext_vector_type(4)));

// ---------------- K0: init + ne + codebook hi/lo B-fragments ----------------
// Grid = 8 blocks x 256 threads.
__global__ __launch_bounds__(256) void k0_init(const float* __restrict__ cb,
                                               float* __restrict__ ne,
                                               int* __restrict__ hist,
                                               double* __restrict__ loss,
                                               bf16x8* __restrict__ cbh,
                                               bf16x8* __restrict__ cbl) {
    int bidx = blockIdx.x, tid = threadIdx.x;

    // ne for codes [bidx*64, bidx*64+64)
    if (tid < 64) {
        int code = bidx * 64 + tid;
        float s = 0.f;
#pragma unroll
        for (int d = 0; d < 64; ++d) { float c = cb[code*64 + d]; s = fmaf(c, c, s); }
        ne[code] = s;
    }
    if (bidx == 0) {
        hist[tid] = 0; hist[tid + 256] = 0;
        if (tid == 0) *loss = 0.0;
    }

    // B-frag element (ct,ks,lane,j) = cb[ct*16 + (lane&15)][ks*32 + (lane>>4)*8 + j]
    // This block handles ct in [bidx*4, bidx*4+4): 512 frag-pairs, 2 per thread.
#pragma unroll
    for (int p = 0; p < 2; ++p) {
        int e = p * 256 + tid;          // 0..511
        int ct = bidx * 4 + (e >> 7);
        int ks = (e >> 6) & 1;
        int lane = e & 63;
        int code  = ct * 16 + (lane & 15);
        int dbase = ks * 32 + ((lane >> 4) << 3);
        bf16x8 h, l;
#pragma unroll
        for (int j = 0; j < 8; ++j) {
            float v = cb[code * 64 + dbase + j];
            __bf16 hv = (__bf16)v;
            __bf16 lv = (__bf16)(v - (float)hv);
            h[j] = hv; l[j] = lv;
        }
        cbh[(ct * 2 + ks) * 64 + lane] = h;
        cbl[(ct * 2 + ks) * 64 + lane] = l;
    }
}

// ---------------- K_MAIN: stage + MFMA argmin + one-hot + quant + loss ------
// Block = 256 thr = 4 waves = 128 rows (8 row-tiles); grid = 512.
__global__ __launch_bounds__(256) void k_main(const float* __restrict__ in,
                                              const float* __restrict__ cb,
                                              const bf16x8* __restrict__ cbh,
                                              const bf16x8* __restrict__ cbl,
                                              const float* __restrict__ ne,
                                              float* __restrict__ out,
                                              float2* __restrict__ enc2,
                                              int* __restrict__ hist,
                                              double* __restrict__ loss) {
    __shared__ float X[64][129];     // 33 KB; all access patterns <=2-way alias (free)
    __shared__ float ne_s[512];
    __shared__ int   sidx[128];
    int tid = threadIdx.x;
    int n0 = blockIdx.x * 128;
    int b  = n0 >> 12, t0 = n0 & (T_ - 1);

    { // stage x-tile: 8192 floats, 32 per thread, coalesced
        int tl = tid & 127, dg = tid >> 7;
#pragma unroll
        for (int i = 0; i < 32; ++i) {
            int d = dg * 32 + i;
            X[d][tl] = in[((size_t)b * 64 + d) * T_ + t0 + tl];
        }
    }
    ne_s[tid] = ne[tid];
    ne_s[tid + 256] = ne[tid + 256];
    __syncthreads();

    int w = tid >> 6, lane = tid & 63;
    int col = lane & 15, q = lane >> 4;

    // A-frags: A[m][k=ks*32+q*8+j] = x_row[d], hi/lo bf16 split
    bf16x8 Ah[2][2], Al[2][2];
#pragma unroll
    for (int r = 0; r < 2; ++r) {
        int rl = (w * 2 + r) * 16 + col;      // local row
#pragma unroll
        for (int ks = 0; ks < 2; ++ks) {
            bf16x8 h, l;
#pragma unroll
            for (int j = 0; j < 8; ++j) {
                float v = X[ks * 32 + q * 8 + j][rl];
                __bf16 hv = (__bf16)v;
                __bf16 lv = (__bf16)(v - (float)hv);
                h[j] = hv; l[j] = lv;
            }
            Ah[r][ks] = h; Al[r][ks] = l;
        }
    }

    float m1[2][4]; int i1[2][4];
#pragma unroll
    for (int r = 0; r < 2; ++r)
#pragma unroll
        for (int e = 0; e < 4; ++e) { m1[r][e] = 3.4e38f; i1[r][e] = 0; }

    for (int ct = 0; ct < 32; ++ct) {
        bf16x8 Bh0 = cbh[(ct * 2 + 0) * 64 + lane];
        bf16x8 Bh1 = cbh[(ct * 2 + 1) * 64 + lane];
        bf16x8 Bl0 = cbl[(ct * 2 + 0) * 64 + lane];
        bf16x8 Bl1 = cbl[(ct * 2 + 1) * 64 + lane];
        float nev = ne_s[ct * 16 + col];
        int code = ct * 16 + col;
#pragma unroll
        for (int r = 0; r < 2; ++r) {
            f32x4 acc = {0.f, 0.f, 0.f, 0.f};
            acc = __builtin_amdgcn_mfma_f32_16x16x32_bf16(Ah[r][0], Bh0, acc, 0, 0, 0);
            acc = __builtin_amdgcn_mfma_f32_16x16x32_bf16(Ah[r][1], Bh1, acc, 0, 0, 0);
            acc = __builtin_amdgcn_mfma_f32_16x16x32_bf16(Ah[r][0], Bl0, acc, 0, 0, 0);
            acc = __builtin_amdgcn_mfma_f32_16x16x32_bf16(Al[r][0], Bh0, acc, 0, 0, 0);
            acc = __builtin_amdgcn_mfma_f32_16x16x32_bf16(Ah[r][1], Bl1, acc, 0, 0, 0);
            acc = __builtin_amdgcn_mfma_f32_16x16x32_bf16(Al[r][1], Bh1, acc, 0, 0, 0);
            // lo*lo terms ~2^-32 relative: negligible, dropped
#pragma unroll
            for (int e = 0; e < 4; ++e) {
                float sc = fmaf(-2.f, acc[e], nev);   // ||e||^2 - 2 x.e
                bool lt = sc < m1[r][e];
                i1[r][e] = lt ? code : i1[r][e];
                m1[r][e] = lt ? sc : m1[r][e];
            }
        }
    }

    // argmin across the 16 lanes (same q) holding this row's columns
#pragma unroll
    for (int r = 0; r < 2; ++r)
#pragma unroll
        for (int e = 0; e < 4; ++e) {
            float a1 = m1[r][e]; int ai = i1[r][e];
#pragma unroll
            for (int off = 1; off < 16; off <<= 1) {
                float o1 = __shfl_xor(a1, off);
                int   oi = __shfl_xor(ai, off);
                bool tk = (o1 < a1) || (o1 == a1 && oi < ai);  // tie -> lower index
                a1 = tk ? o1 : a1; ai = tk ? oi : ai;
            }
            if (col == 0) sidx[(w * 2 + r) * 16 + q * 4 + e] = ai;
        }
    __syncthreads();

    // --- one-hot rows: 256 float2 cols per row, 128 rows ---
#pragma unroll 4
    for (int i = 0; i < 128; ++i) {
        int id = sidx[i];                      // uniform LDS read -> broadcast
        float2 v;
        v.x = ((id >> 1) == tid && (id & 1) == 0) ? 1.f : 0.f;
        v.y = ((id >> 1) == tid && (id & 1) == 1) ? 1.f : 0.f;
        enc2[(size_t)(n0 + i) * 256 + tid] = v;
    }

    // --- quantized + loss: lane = row, 32 dims per thread ---
    int tl = tid & 127, dg = tid >> 7;
    int idq = sidx[tl];
    const float4* cq4 = (const float4*)(cb + (size_t)idq * 64 + dg * 32);
    float* qp = out + 1 + (size_t)b * D_ * T_ + (size_t)(dg * 32) * T_ + t0 + tl;

    float lsum = 0.f;
#pragma unroll
    for (int j4 = 0; j4 < 8; ++j4) {
        float4 qv = cq4[j4];
        float qe[4] = {qv.x, qv.y, qv.z, qv.w};
#pragma unroll
        for (int e = 0; e < 4; ++e) {
            int dl = j4 * 4 + e;               // 0..31
            float xv = X[dg * 32 + dl][tl];
            float diff = qe[e] - xv;
            lsum = fmaf(diff, diff, lsum);
            qp[(size_t)dl * T_] = xv + diff;   // straight-through: x + (q - x)
        }
    }
    if (tid < 128) atomicAdd(&hist[idq], 1);   // one count per row

#pragma unroll
    for (int off = 32; off > 0; off >>= 1) lsum += __shfl_down(lsum, off);
    __shared__ float wsum[4];
    if ((tid & 63) == 0) wsum[tid >> 6] = lsum;
    __syncthreads();
    if (tid == 0) {
        double s = (double)wsum[0] + (double)wsum[1] + (double)wsum[2] + (double)wsum[3];
        atomicAdd(loss, s);
    }
}

// ---------------- K6: finalize loss + perplexity ----------------------------
__global__ __launch_bounds__(512) void k6_final(const int* __restrict__ hist,
                                                const double* __restrict__ loss,
                                                float* __restrict__ out) {
    __shared__ double sh[512];
    int k = threadIdx.x;
    double p = (double)hist[k] / (double)N_;
    sh[k] = p * log(p + 1e-10);
    __syncthreads();
    for (int s = 256; s > 0; s >>= 1) {
        if (k < s) sh[k] += sh[k + s];
        __syncthreads();
    }
    if (k == 0) {
        out[1 + Q_] = (float)exp(-sh[0]);
        out[0] = (float)(1.25 * (*loss) / (double)Q_);
    }
}

extern "C" void kernel_launch(void* const* d_in, const int* in_sizes, int n_in,
                              void* d_out, int out_size, void* d_ws, size_t ws_size,
                              hipStream_t stream) {
    const float* in = (const float*)d_in[0];   // [16, 64, 4096] fp32
    const float* cb = (const float*)d_in[1];   // [512, 64] fp32
    float* out = (float*)d_out;
    char* ws = (char*)d_ws;

    double* loss  = (double*)(ws + WS_LOSS);
    int* hist     = (int*)(ws + WS_HIST);
    float* ne     = (float*)(ws + WS_NE);
    bf16x8* cbh   = (bf16x8*)(ws + WS_CBH);
    bf16x8* cbl   = (bf16x8*)(ws + WS_CBL);

    float2* enc2 = (float2*)(out + ENC_OFF);

    k0_init<<<8, 256, 0, stream>>>(cb, ne, hist, loss, cbh, cbl);
    k_main<<<512, 256, 0, stream>>>(in, cb, cbh, cbl, ne, out, enc2, hist, loss);
    k6_final<<<1, 512, 0, stream>>>(hist, loss, out);
}